// Round 4
// baseline (253.745 us; speedup 1.0000x reference)
//
#include <hip/hip_runtime.h>
#include <hip/hip_bf16.h>

// Gathered skinny GEMM: out[b, r] = sum_d x[b,d] * w[indices[r], d]
//   x: [32][4096] f32, w: [11008][4096] f32, indices: [4403] i32,
//   out: [32][4403] f32
//
// R9: R8 (253us, slice ~36) failed on RESIDENCY: 1024-thr blocks = 16 waves
// = one block/CU at 128 VGPR, so grid 276 left 20 CUs running a SERIALIZED
// second block (~T_block tail). Fix: same single-kernel full-K-per-block
// structure, but 512-thr blocks with __launch_bounds__(512,4):
//   - 276 blocks x 8 waves; wave w owns K-chunk w*512 (KSTEPS=16).
//   - VGPR capped at 128 -> 2 blocks/CU resident -> ALL 276 blocks
//     co-resident (512 slots); the 20 double-loaded CUs overlap both blocks
//     from t=0; kernel is one saturated HBM stream, no serial tail.
//   - 8-wave LDS reduce (16 KB/block; 32 KB/CU at 2 blocks) -> plain masked
//     stores. No atomics, no memset, no p0/p2, ONE dispatch.
//   - unroll 2: ~80-90 live VGPR; unroll 4 would blow the 128 cap.
// Floor: ~3630 unique gathered rows (dups L3-absorbed) = 58-66 MB HBM
// @ 6.3 TB/s ~= 10-11us; x f32 L2 traffic (141 MB @ 34.5 TB/s) overlaps.
// MFMA layout (16x16x32 bf16, per m89/m91/m120):
//   A = gathered W rows: lane(quad=l>>4, m=l&15) reads
//       W[idx[rt*16+m]][k0 + s*32 + quad*8 + 0..7] (32 B contiguous), cvt bf16.
//   B = x rows b=m and b=m+16, same k-slice, cvt bf16.
//   D: lane holds D[r_local=quad*4+j][b=lane&15 (+16 for acc1)].

#define D_MODEL   4096
#define REMAINED  4403
#define BATCH     32
#define RT16      ((REMAINED + 15) / 16)  // 276 r-tiles
#define WAVES     8
#define KCHUNK    (D_MODEL / WAVES)       // 512 floats per wave
#define KSTEPS    (KCHUNK / 32)           // 16 MFMA k-steps per wave
#define BLOCK     (WAVES * 64)            // 512
#define GRID1     RT16                    // 276 blocks, all co-resident

typedef __attribute__((ext_vector_type(8))) short  short8;   // 8 bf16
typedef __attribute__((ext_vector_type(4))) float  floatx4;  // 4 fp32 acc

union ABFrag { short8 s8; __hip_bfloat162 h2[4]; };

__device__ __forceinline__ short8 cvt8(const float4 a, const float4 b) {
    ABFrag f;
    f.h2[0] = __float22bfloat162_rn(make_float2(a.x, a.y));
    f.h2[1] = __float22bfloat162_rn(make_float2(a.z, a.w));
    f.h2[2] = __float22bfloat162_rn(make_float2(b.x, b.y));
    f.h2[3] = __float22bfloat162_rn(make_float2(b.z, b.w));
    return f.s8;
}

__global__ __launch_bounds__(BLOCK, 4) void p1_mfma(
    const float* __restrict__ w,
    const int*   __restrict__ idx,
    const float* __restrict__ x,
    float*       __restrict__ out)
{
    const int warp = (int)threadIdx.x >> 6;
    const int lane = (int)threadIdx.x & 63;
    const int quad = lane >> 4;
    const int m    = lane & 15;

    const int rt = (int)blockIdx.x;
    const int k0 = warp * KCHUNK;          // this wave's K origin (floats)

    // gathered W row for this lane's A-fragment rows
    const int r   = rt * 16 + m;
    const int rc  = (r < REMAINED) ? r : (REMAINED - 1);  // padded rows: dup,
    const int row = idx[rc];                              // masked at the store

    // per step s: lane reads W[row][k0 + s*32 + quad*8 + 0..7]
    const float4* __restrict__ wp =
        (const float4*)(w + (size_t)row * D_MODEL + k0) + quad * 2;

    // B operands: x[b][same k-slice] as f32 (L2-resident), b = m and m+16
    const float4* __restrict__ xp0 =
        (const float4*)(x + (size_t)m * D_MODEL + k0) + quad * 2;
    const float4* __restrict__ xp1 =
        (const float4*)(x + (size_t)(m + 16) * D_MODEL + k0) + quad * 2;

    floatx4 acc0 = {0.f, 0.f, 0.f, 0.f};
    floatx4 acc1 = {0.f, 0.f, 0.f, 0.f};

#pragma unroll 2
    for (int s = 0; s < KSTEPS; ++s) {
        const float4 w0 = wp[s * 8 + 0];
        const float4 w1 = wp[s * 8 + 1];
        const float4 a0 = xp0[s * 8 + 0];
        const float4 a1 = xp0[s * 8 + 1];
        const float4 b0 = xp1[s * 8 + 0];
        const float4 b1 = xp1[s * 8 + 1];

        const short8 af = cvt8(w0, w1);
        const short8 x0 = cvt8(a0, a1);
        const short8 x1 = cvt8(b0, b1);

        acc0 = __builtin_amdgcn_mfma_f32_16x16x32_bf16(af, x0, acc0, 0, 0, 0);
        acc1 = __builtin_amdgcn_mfma_f32_16x16x32_bf16(af, x1, acc1, 0, 0, 0);
    }

    // ---- on-chip reduction of the 8 waves' k-partials --------------------
    // red[w][b*16 + r_local]; lane holds D[r_local=quad*4+j][b] for b=m, m+16
    __shared__ float red[WAVES][BATCH * 16];

    float4* lp = (float4*)red[warp];
    lp[m * 4 + quad]        = make_float4(acc0[0], acc0[1], acc0[2], acc0[3]);
    lp[(m + 16) * 4 + quad] = make_float4(acc1[0], acc1[1], acc1[2], acc1[3]);
    __syncthreads();

    // 512 outputs, 512 threads: one each (stride-1 LDS reads = free 2-way)
    const int e = (int)threadIdx.x;
    float s = 0.f;
#pragma unroll
    for (int v = 0; v < WAVES; ++v) s += red[v][e];

    const int b  = e >> 4;
    const int rl = e & 15;
    const int rr = rt * 16 + rl;
    if (rr < REMAINED) out[(size_t)b * REMAINED + rr] = s;
}

extern "C" void kernel_launch(void* const* d_in, const int* in_sizes, int n_in,
                              void* d_out, int out_size, void* d_ws, size_t ws_size,
                              hipStream_t stream) {
    const float* x   = (const float*)d_in[0];
    const float* w   = (const float*)d_in[1];
    const int*   idx = (const int*)d_in[2];
    float*       out = (float*)d_out;

    (void)d_ws; (void)ws_size;

    p1_mfma<<<GRID1, BLOCK, 0, stream>>>(w, idx, x, out);
}

// Round 5
// 241.656 us; speedup vs baseline: 1.0500x; 1.0500x over previous
//
#include <hip/hip_runtime.h>
#include <hip/hip_bf16.h>

// Gathered skinny GEMM: out[b, r] = sum_d x[b,d] * w[indices[r], d]
//   x: [32][4096] f32, w: [11008][4096] f32, indices: [4403] i32,
//   out: [32][4403] f32
//
// R10: R7-R9 all lost to R5 because they halved TOTAL WAVES (2208 vs 4416).
// The gather is latency-bound and scales with resident wave count (Little's
// law: 6.3 TB/s x ~375ns HBM latency needs ~2.4 MB in flight; a wave carries
// ~4 KB). R10 returns to the proven R5 geometry -- 1104 blocks x 4 waves =
// 4416 waves, KSTEPS=8 per wave -- and shaves only overheads:
//   - p0 fused: x loaded f32 (L2-resident; ~18 MB/XCD over the kernel's
//     lifetime << L2 BW), cvt bf16 in-register. One less launch.
//   - block = (rt, kq): 4 waves cover one K-QUARTER; in-block LDS reduce
//     cuts partial planes 16 -> 4 (9 MB -> 2.26 MB each way).
//   - p2 = R5's proven reduce with KSPLIT=4 (138 blocks). No atomics.
//   - no min-wave launch_bounds (R9's (512,4) VGPR squeeze is a regression
//     suspect); plain 256-thread blocks, ~90-110 VGPR, 4+ blocks/CU.
// Floor: ~60-70 MB gathered W @ 6.3 TB/s ~= 11us + ~4us of reduce/launch.
// MFMA layout (16x16x32 bf16, per m89/m91/m120):
//   A = gathered W rows: lane(quad=l>>4, m=l&15) reads
//       W[idx[rt*16+m]][k0 + s*32 + quad*8 + 0..7] (32 B contiguous), cvt bf16.
//   B = x rows b=m and b=m+16, same k-slice, cvt bf16.
//   D: lane holds D[r_local=quad*4+j][b=lane&15 (+16 for acc1)].

#define D_MODEL   4096
#define REMAINED  4403
#define BATCH     32
#define RT16      ((REMAINED + 15) / 16)  // 276 r-tiles
#define RSLOTS    (RT16 * 16)             // 4416 padded rows
#define KQ        4                       // k-quarters (one per block)
#define WAVES     4                       // waves per block
#define KCHUNK    (D_MODEL / KQ / WAVES)  // 256 floats per wave
#define KSTEPS    (KCHUNK / 32)           // 8 MFMA k-steps per wave
#define BLOCK     (WAVES * 64)            // 256
#define GRID1     (RT16 * KQ)             // 1104 blocks = 4416 waves

typedef __attribute__((ext_vector_type(8))) short  short8;   // 8 bf16
typedef __attribute__((ext_vector_type(4))) float  floatx4;  // 4 fp32 acc

union ABFrag { short8 s8; __hip_bfloat162 h2[4]; };

__device__ __forceinline__ short8 cvt8(const float4 a, const float4 b) {
    ABFrag f;
    f.h2[0] = __float22bfloat162_rn(make_float2(a.x, a.y));
    f.h2[1] = __float22bfloat162_rn(make_float2(a.z, a.w));
    f.h2[2] = __float22bfloat162_rn(make_float2(b.x, b.y));
    f.h2[3] = __float22bfloat162_rn(make_float2(b.z, b.w));
    return f.s8;
}

// ---- p1: gathered MFMA GEMM, 4-wave LDS reduce, quarter-K partials ----
__global__ __launch_bounds__(BLOCK) void p1_mfma(
    const float* __restrict__ w,
    const int*   __restrict__ idx,
    const float* __restrict__ x,
    float*       __restrict__ partial)
{
    const int warp = (int)threadIdx.x >> 6;
    const int lane = (int)threadIdx.x & 63;
    const int quad = lane >> 4;
    const int m    = lane & 15;

    const int rt = (int)blockIdx.x % RT16;
    const int kq = (int)blockIdx.x / RT16;
    const int k0 = (kq * WAVES + warp) * KCHUNK;   // wave's K origin (floats)

    // gathered W row for this lane's A-fragment rows
    const int r   = rt * 16 + m;
    const int rc  = (r < REMAINED) ? r : (REMAINED - 1);  // padded rows: dup,
    const int row = idx[rc];                              // masked in p2

    // per step s: lane reads W[row][k0 + s*32 + quad*8 + 0..7]
    const float4* __restrict__ wp =
        (const float4*)(w + (size_t)row * D_MODEL + k0) + quad * 2;

    // B operands: x[b][same k-slice] as f32 (L2-resident), b = m and m+16
    const float4* __restrict__ xp0 =
        (const float4*)(x + (size_t)m * D_MODEL + k0) + quad * 2;
    const float4* __restrict__ xp1 =
        (const float4*)(x + (size_t)(m + 16) * D_MODEL + k0) + quad * 2;

    floatx4 acc0 = {0.f, 0.f, 0.f, 0.f};
    floatx4 acc1 = {0.f, 0.f, 0.f, 0.f};

#pragma unroll 2
    for (int s = 0; s < KSTEPS; ++s) {
        const float4 w0 = wp[s * 8 + 0];
        const float4 w1 = wp[s * 8 + 1];
        const float4 a0 = xp0[s * 8 + 0];
        const float4 a1 = xp0[s * 8 + 1];
        const float4 b0 = xp1[s * 8 + 0];
        const float4 b1 = xp1[s * 8 + 1];

        const short8 af = cvt8(w0, w1);
        const short8 x0 = cvt8(a0, a1);
        const short8 x1 = cvt8(b0, b1);

        acc0 = __builtin_amdgcn_mfma_f32_16x16x32_bf16(af, x0, acc0, 0, 0, 0);
        acc1 = __builtin_amdgcn_mfma_f32_16x16x32_bf16(af, x1, acc1, 0, 0, 0);
    }

    // ---- in-block reduction of the 4 waves' k-partials -------------------
    // red[w][b*16 + r_local]; lane holds D[r_local=quad*4+j][b] for b=m, m+16
    __shared__ float red[WAVES][BATCH * 16];

    float4* lp = (float4*)red[warp];
    lp[m * 4 + quad]        = make_float4(acc0[0], acc0[1], acc0[2], acc0[3]);
    lp[(m + 16) * 4 + quad] = make_float4(acc1[0], acc1[1], acc1[2], acc1[3]);
    __syncthreads();

    // 512 outputs / 256 threads = 2 each; partial[kq][b][rslot]
#pragma unroll
    for (int h = 0; h < 2; ++h) {
        const int e = (int)threadIdx.x + h * BLOCK;
        const float s = (red[0][e] + red[1][e]) + (red[2][e] + red[3][e]);
        const int b  = e >> 4;
        const int rl = e & 15;
        partial[((size_t)kq * BATCH + b) * RSLOTS + rt * 16 + rl] = s;
    }
}

// ---- p2: reduce KQ planes, masked write ------------------------------
#define GRID2  ((BATCH * (RSLOTS / 4)) / BLOCK)      // 32*1104/256 = 138

__global__ __launch_bounds__(BLOCK) void p2_reduce(
    const float* __restrict__ partial,
    float*       __restrict__ out)
{
    const int g  = blockIdx.x * BLOCK + threadIdx.x;  // 0..35327
    const int b  = g / (RSLOTS / 4);
    const int r4 = g % (RSLOTS / 4);

    const float4* p = (const float4*)partial + ((size_t)b * (RSLOTS / 4) + r4);

    float4 s = make_float4(0.f, 0.f, 0.f, 0.f);
#pragma unroll
    for (int kq = 0; kq < KQ; ++kq) {
        const float4 v = p[(size_t)kq * BATCH * (RSLOTS / 4)];
        s.x += v.x; s.y += v.y; s.z += v.z; s.w += v.w;
    }

    const int r0 = r4 * 4;
    float* o = out + (size_t)b * REMAINED;
    if (r0 + 3 < REMAINED) {
        *(float4*)(o + r0) = s;
    } else {
        if (r0 + 0 < REMAINED) o[r0 + 0] = s.x;
        if (r0 + 1 < REMAINED) o[r0 + 1] = s.y;
        if (r0 + 2 < REMAINED) o[r0 + 2] = s.z;
        if (r0 + 3 < REMAINED) o[r0 + 3] = s.w;
    }
}

extern "C" void kernel_launch(void* const* d_in, const int* in_sizes, int n_in,
                              void* d_out, int out_size, void* d_ws, size_t ws_size,
                              hipStream_t stream) {
    const float* x   = (const float*)d_in[0];
    const float* w   = (const float*)d_in[1];
    const int*   idx = (const int*)d_in[2];
    float*       out = (float*)d_out;

    float* partial = (float*)d_ws;   // KQ*BATCH*RSLOTS*4 = 2.26 MB

    p1_mfma  <<<GRID1, BLOCK, 0, stream>>>(w, idx, x, partial);
    p2_reduce<<<GRID2, BLOCK, 0, stream>>>(partial, out);
}

// Round 6
// 239.791 us; speedup vs baseline: 1.0582x; 1.0078x over previous
//
#include <hip/hip_runtime.h>
#include <hip/hip_bf16.h>

// Gathered skinny GEMM: out[b, r] = sum_d x[b,d] * w[indices[r], d]
//   x: [32][4096] f32, w: [11008][4096] f32, indices: [4403] i32,
//   out: [32][4403] f32
//
// R11: consolidation. Ledger: R5=239.2 (best), R6 atomics=274, R7/R9 half
// waves=246/254, R8 serial tail=253, R10 f32-x+unroll2=241.7. Every change
// to R5's p1 BODY regressed; only overheads are worth attacking.
// R11 = R5's p1 body VERBATIM (bf16-x short8 loads, full unroll, 1104 blocks
// x 4 waves = 4416 waves, plain launch_bounds(256)) with ONE isolated change:
//   - epilogue: 4-wave in-block LDS reduce (R10-validated) -> partial planes
//     16 -> 4. Partial traffic 9 MB -> 2.26 MB each way (~2us HBM saved),
//     p2 4x lighter. Block = (rt, kq): 4 waves span one K-quarter.
//   - p0 restored (x -> bf16 once, 256 KB): halves B-operand bytes in p1 and
//     removes 2 of 3 cvt8 chains per step -- the R5-proven memory engine.
// Floor: ~60-72 MB gathered W @ 6.3 TB/s ~= 10-11.5us + ~4us overheads;
// harness fills (2 x ~108.5us) dominate the 241.7 total regardless.
// MFMA layout (16x16x32 bf16, per m89/m91/m120):
//   A = gathered W rows: lane(quad=l>>4, m=l&15) reads
//       W[idx[rt*16+m]][k0 + s*32 + quad*8 + 0..7] (32 B contiguous), cvt bf16.
//   B = x_bf16 rows b=m and b=m+16, same k-slice (16 B contiguous short8).
//   D: lane holds D[r_local=quad*4+j][b=lane&15 (+16 for acc1)].

#define D_MODEL   4096
#define REMAINED  4403
#define BATCH     32
#define RT16      ((REMAINED + 15) / 16)  // 276 r-tiles
#define RSLOTS    (RT16 * 16)             // 4416 padded rows
#define KQ        4                       // k-quarters (one per block)
#define WAVES     4                       // waves per block
#define KCHUNK    (D_MODEL / KQ / WAVES)  // 256 floats per wave
#define KSTEPS    (KCHUNK / 32)           // 8 MFMA k-steps per wave
#define BLOCK     (WAVES * 64)            // 256
#define GRID1     (RT16 * KQ)             // 1104 blocks = 4416 waves

// ws layout: [0, 256KB)           x_bf16 [32][4096]
//            [256KB, 256KB+2.26MB) partial [KQ][BATCH][RSLOTS] fp32
#define XB_ELEMS   (BATCH * D_MODEL)                 // 131072
#define PART_OFF   (XB_ELEMS * 2)                    // bytes: 256 KB

typedef __attribute__((ext_vector_type(8))) short  short8;   // 8 bf16
typedef __attribute__((ext_vector_type(4))) float  floatx4;  // 4 fp32 acc

union ABFrag { short8 s8; __hip_bfloat162 h2[4]; };

// ---- p0: convert x to bf16 (RNE) ------------------------------------
__global__ __launch_bounds__(BLOCK) void p0_cvt(
    const float* __restrict__ x, __hip_bfloat16* __restrict__ xb)
{
    const int i = blockIdx.x * BLOCK + threadIdx.x;  // 0..32767, 4 floats each
    const float4 v = ((const float4*)x)[i];
    __hip_bfloat162* o = (__hip_bfloat162*)xb;
    o[2 * i + 0] = __float22bfloat162_rn(make_float2(v.x, v.y));
    o[2 * i + 1] = __float22bfloat162_rn(make_float2(v.z, v.w));
}

// ---- p1: gathered MFMA GEMM (R5 body) + 4-wave LDS reduce -----------
__global__ __launch_bounds__(BLOCK) void p1_mfma(
    const float* __restrict__ w,
    const int*   __restrict__ idx,
    const __hip_bfloat16* __restrict__ xb,
    float*       __restrict__ partial)
{
    const int warp = (int)threadIdx.x >> 6;
    const int lane = (int)threadIdx.x & 63;
    const int quad = lane >> 4;
    const int m    = lane & 15;

    const int rt = (int)blockIdx.x % RT16;
    const int kq = (int)blockIdx.x / RT16;
    const int k0 = (kq * WAVES + warp) * KCHUNK;   // wave's K origin (floats)

    // gathered W row for this lane's A-fragment rows
    const int r   = rt * 16 + m;
    const int rc  = (r < REMAINED) ? r : (REMAINED - 1);  // padded rows: dup,
    const int row = idx[rc];                              // masked in p2

    // per step s: lane reads W[row][k0 + s*32 + quad*8 + 0..7]
    const float4* __restrict__ wp =
        (const float4*)(w + (size_t)row * D_MODEL + k0) + quad * 2;

    // B fragments: x_bf16[b][k0 + s*32 + quad*8 + 0..7], b-tiles m / m+16
    const short8* __restrict__ xp0 =
        (const short8*)(xb + (size_t)m * D_MODEL + k0) + quad;
    const short8* __restrict__ xp1 =
        (const short8*)(xb + (size_t)(m + 16) * D_MODEL + k0) + quad;

    floatx4 acc0 = {0.f, 0.f, 0.f, 0.f};
    floatx4 acc1 = {0.f, 0.f, 0.f, 0.f};

#pragma unroll
    for (int s = 0; s < KSTEPS; ++s) {
        const float4 w0 = wp[s * 8 + 0];
        const float4 w1 = wp[s * 8 + 1];
        const short8 b0 = xp0[s * 4];
        const short8 b1 = xp1[s * 4];

        ABFrag af;
        af.h2[0] = __float22bfloat162_rn(make_float2(w0.x, w0.y));
        af.h2[1] = __float22bfloat162_rn(make_float2(w0.z, w0.w));
        af.h2[2] = __float22bfloat162_rn(make_float2(w1.x, w1.y));
        af.h2[3] = __float22bfloat162_rn(make_float2(w1.z, w1.w));

        acc0 = __builtin_amdgcn_mfma_f32_16x16x32_bf16(af.s8, b0, acc0, 0, 0, 0);
        acc1 = __builtin_amdgcn_mfma_f32_16x16x32_bf16(af.s8, b1, acc1, 0, 0, 0);
    }

    // ---- in-block reduction of the 4 waves' k-partials -------------------
    // red[w][b*16 + r_local]; lane holds D[r_local=quad*4+j][b] for b=m, m+16
    __shared__ float red[WAVES][BATCH * 16];

    float4* lp = (float4*)red[warp];
    lp[m * 4 + quad]        = make_float4(acc0[0], acc0[1], acc0[2], acc0[3]);
    lp[(m + 16) * 4 + quad] = make_float4(acc1[0], acc1[1], acc1[2], acc1[3]);
    __syncthreads();

    // 512 outputs / 256 threads = 2 each; partial[kq][b][rslot]
#pragma unroll
    for (int h = 0; h < 2; ++h) {
        const int e = (int)threadIdx.x + h * BLOCK;
        const float s = (red[0][e] + red[1][e]) + (red[2][e] + red[3][e]);
        const int b  = e >> 4;
        const int rl = e & 15;
        partial[((size_t)kq * BATCH + b) * RSLOTS + rt * 16 + rl] = s;
    }
}

// ---- p2: reduce KQ planes, masked write ------------------------------
#define GRID2  ((BATCH * (RSLOTS / 4)) / BLOCK)      // 32*1104/256 = 138

__global__ __launch_bounds__(BLOCK) void p2_reduce(
    const float* __restrict__ partial,
    float*       __restrict__ out)
{
    const int g  = blockIdx.x * BLOCK + threadIdx.x;  // 0..35327
    const int b  = g / (RSLOTS / 4);
    const int r4 = g % (RSLOTS / 4);

    const float4* p = (const float4*)partial + ((size_t)b * (RSLOTS / 4) + r4);

    float4 s = make_float4(0.f, 0.f, 0.f, 0.f);
#pragma unroll
    for (int kq = 0; kq < KQ; ++kq) {
        const float4 v = p[(size_t)kq * BATCH * (RSLOTS / 4)];
        s.x += v.x; s.y += v.y; s.z += v.z; s.w += v.w;
    }

    const int r0 = r4 * 4;
    float* o = out + (size_t)b * REMAINED;
    if (r0 + 3 < REMAINED) {
        *(float4*)(o + r0) = s;
    } else {
        if (r0 + 0 < REMAINED) o[r0 + 0] = s.x;
        if (r0 + 1 < REMAINED) o[r0 + 1] = s.y;
        if (r0 + 2 < REMAINED) o[r0 + 2] = s.z;
        if (r0 + 3 < REMAINED) o[r0 + 3] = s.w;
    }
}

extern "C" void kernel_launch(void* const* d_in, const int* in_sizes, int n_in,
                              void* d_out, int out_size, void* d_ws, size_t ws_size,
                              hipStream_t stream) {
    const float* x   = (const float*)d_in[0];
    const float* w   = (const float*)d_in[1];
    const int*   idx = (const int*)d_in[2];
    float*       out = (float*)d_out;

    __hip_bfloat16* xb      = (__hip_bfloat16*)d_ws;
    float*          partial = (float*)((char*)d_ws + PART_OFF);

    p0_cvt   <<<XB_ELEMS / 4 / BLOCK, BLOCK, 0, stream>>>(x, xb);   // 128 blocks
    p1_mfma  <<<GRID1, BLOCK, 0, stream>>>(w, idx, xb, partial);
    p2_reduce<<<GRID2, BLOCK, 0, stream>>>(partial, out);
}